// Round 4
// baseline (1693.301 us; speedup 1.0000x reference)
//
#include <hip/hip_runtime.h>
#include <hip/hip_fp16.h>
#include <math.h>

#define N_NODES 200000
#define N_EDGES 6400000
#define T 6
#define M 10

// CSR build configuration: 256-node buckets, chunked counting sort.
#define NB    782            // ceil(200000/256) buckets (dst>>8)
#define NBLK  256            // edge chunks == CU count
#define CH    25000          // edges per chunk (256*25000 = 6.4M exact)
#define GHLEN (NB * NBLK)    // 200192

#define SBLOCKS 196          // ceil(GHLEN/1024) scan blocks

// passC dynamic LDS: edge array (CH) + cnt/ls/lcur/gs (4*NB) + scan buf (1024)
#define PASSC_LDS_INTS  (CH + 4 * NB + 1024)
#define PASSC_LDS_BYTES (PASSC_LDS_INTS * 4)   // 116,608 B < 160 KiB/CU

#define ASTRIDE 11           // acc row stride: gcd(11,32)=1 -> conflict-free banks

typedef __attribute__((ext_vector_type(2))) float vf2;
typedef __attribute__((ext_vector_type(4))) unsigned int u32x4;

// ---------------------------------------------------------------------------
// convert x_member [N,6] fp32 -> xh [N,8] fp16 (zero-padded), 16 B rows.
// ---------------------------------------------------------------------------
__global__ __launch_bounds__(256) void convert_kernel(
    const float* __restrict__ x, __half* __restrict__ xh)
{
    int i = blockIdx.x * 256 + threadIdx.x;
    if (i >= N_NODES) return;
    const vf2* p = (const vf2*)(x + (size_t)i * 6);   // rows 24B -> 8B aligned
    vf2 a = __builtin_nontemporal_load(p);
    vf2 b = __builtin_nontemporal_load(p + 1);
    vf2 c = __builtin_nontemporal_load(p + 2);
    union { __half2 h[4]; u32x4 q; } u;
    u.h[0] = __floats2half2_rn(a.x, a.y);
    u.h[1] = __floats2half2_rn(b.x, b.y);
    u.h[2] = __floats2half2_rn(c.x, c.y);
    u.h[3] = __floats2half2_rn(0.f, 0.f);
    __builtin_nontemporal_store(u.q, (u32x4*)(xh + (size_t)i * 8));
}

// ---------------------------------------------------------------------------
// Pass A: per-chunk bucket histogram -> gh[bucket*NBLK + chunk]
// ---------------------------------------------------------------------------
__global__ __launch_bounds__(1024) void passA_kernel(
    const int* __restrict__ dst, int* __restrict__ gh)
{
    __shared__ int lh[NB];
    int g = blockIdx.x;
    for (int t = threadIdx.x; t < NB; t += 1024) lh[t] = 0;
    __syncthreads();
    int base = g * CH;
    int end  = base + CH; if (end > N_EDGES) end = N_EDGES;
    for (int e = base + threadIdx.x; e < end; e += 1024)
        atomicAdd(&lh[__builtin_nontemporal_load(dst + e) >> 8], 1);
    __syncthreads();
    for (int t = threadIdx.x; t < NB; t += 1024) gh[t * NBLK + g] = lh[t];
}

// ---------------------------------------------------------------------------
// Hierarchical exclusive scan of gh[GHLEN]
// ---------------------------------------------------------------------------
__global__ __launch_bounds__(1024) void scan1_kernel(
    int* __restrict__ gh, int* __restrict__ bsum)
{
    __shared__ int sbuf[1024];
    int tid = threadIdx.x;
    int t   = blockIdx.x * 1024 + tid;
    int v   = (t < GHLEN) ? gh[t] : 0;
    sbuf[tid] = v;
    __syncthreads();
    for (int d = 1; d < 1024; d <<= 1) {
        int u = (tid >= d) ? sbuf[tid - d] : 0;
        __syncthreads();
        sbuf[tid] += u;
        __syncthreads();
    }
    if (t < GHLEN) gh[t] = sbuf[tid] - v;           // local exclusive
    if (tid == 1023) bsum[blockIdx.x] = sbuf[1023]; // block total
}

__global__ __launch_bounds__(256) void scan2_kernel(int* __restrict__ bsum)
{
    __shared__ int sbuf[256];
    int tid = threadIdx.x;
    int v = (tid < SBLOCKS) ? bsum[tid] : 0;
    sbuf[tid] = v;
    __syncthreads();
    for (int d = 1; d < 256; d <<= 1) {
        int u = (tid >= d) ? sbuf[tid - d] : 0;
        __syncthreads();
        sbuf[tid] += u;
        __syncthreads();
    }
    if (tid < SBLOCKS) bsum[tid] = sbuf[tid] - v;   // exclusive
}

__global__ __launch_bounds__(1024) void scan3_kernel(
    int* __restrict__ gh, const int* __restrict__ bsum)
{
    int t = blockIdx.x * 1024 + threadIdx.x;
    if (t < GHLEN) gh[t] += bsum[blockIdx.x];
}

// ---------------------------------------------------------------------------
// Pass C: counting-sort the whole chunk INSIDE LDS, then copy each
// (bucket,chunk) segment out as a contiguous per-wave burst (full-line,
// write-once; scattered 4 B stores cost 5.9x write amp at HBM).
// ---------------------------------------------------------------------------
__global__ __launch_bounds__(1024) void passC_kernel(
    const int* __restrict__ src, const int* __restrict__ dst,
    const int* __restrict__ gh, int* __restrict__ ebuf)
{
    extern __shared__ int dyn[];
    int* earr = dyn;             // [CH]  bucket-sorted packed edges
    int* cnt  = dyn + CH;        // [NB]  edges of bucket b in this chunk
    int* ls   = cnt + NB;        // [NB]  local exclusive start
    int* lcur = ls + NB;         // [NB]  scatter cursor
    int* gs   = lcur + NB;       // [NB]  global segment start
    int* sbuf = gs + NB;         // [1024] scan temp

    int g   = blockIdx.x;
    int tid = threadIdx.x;

    // per-bucket global start + count for this chunk, from scanned gh
    for (int b = tid; b < NB; b += 1024) {
        int idx = b * NBLK + g;
        int s0  = gh[idx];
        int s1  = (idx + 1 < GHLEN) ? gh[idx + 1] : N_EDGES;
        gs[b]  = s0;
        cnt[b] = s1 - s0;
    }
    __syncthreads();

    // exclusive scan of cnt -> ls (NB=782 <= 1024, single pass)
    int v = (tid < NB) ? cnt[tid] : 0;
    sbuf[tid] = v;
    __syncthreads();
    for (int d = 1; d < 1024; d <<= 1) {
        int u = (tid >= d) ? sbuf[tid - d] : 0;
        __syncthreads();
        sbuf[tid] += u;
        __syncthreads();
    }
    if (tid < NB) { int e0 = sbuf[tid] - v; ls[tid] = e0; lcur[tid] = e0; }
    __syncthreads();

    // scatter chunk edges into LDS, bucket-grouped (LDS atomics only)
    int base = g * CH;
    for (int e = base + tid; e < base + CH; e += 1024) {
        int s = __builtin_nontemporal_load(src + e);
        int d = __builtin_nontemporal_load(dst + e);
        int b = d >> 8;
        int p = atomicAdd(&lcur[b], 1);
        earr[p] = (s << 8) | (d & 255);
    }
    __syncthreads();

    // coalesced copy-out: one wave per bucket segment (mean 32 edges = 128 B)
    int wv = tid >> 6, lane = tid & 63;
    for (int b = wv; b < NB; b += 16) {
        int bl = ls[b], bg = gs[b], c = cnt[b];
        for (int o = lane; o < c; o += 64)
            ebuf[bg + o] = earr[bl + o];   // normal store: L2 merges the
    }                                      // chunk-boundary-shared lines
}

// ---------------------------------------------------------------------------
// round, v3: scatter-accumulate into per-dst LDS accumulators.
//
// Why: segment-sum is commutative, so the node-level counting sort (passD,
// 55 us) existed only to let each lane walk "its" segment. Instead: block =
// bucket (256 dst nodes); zero acc[256][11] f32 in LDS; stream the bucket's
// contiguous packed edges (dwordx4 NT, 4 gathers/lane in flight); decode
// in[src]; ds_add_f32 into acc[dst&255][*]. passD + off are DELETED, degree
// divergence is gone (edges striped evenly), and 512-thread blocks with
// 11.6 KB LDS give ~24 waves/CU (was 27% occ) to hide the L2 gather latency.
// ASTRIDE=11: gcd(11,32)=1 -> per-instr banks conflict-free up to the
// unavoidable same-dst collisions (~8 pairs/instr, birthday over 256).
// ---------------------------------------------------------------------------
template<int TD, bool FP8IN>
__device__ inline void decode_row(u32x4 q, float* f)
{
    if (FP8IN) {
        vf2 f0 = __builtin_amdgcn_cvt_pk_f32_fp8(q.x, false);
        vf2 f1 = __builtin_amdgcn_cvt_pk_f32_fp8(q.x, true);
        vf2 f2 = __builtin_amdgcn_cvt_pk_f32_fp8(q.y, false);
        vf2 f3 = __builtin_amdgcn_cvt_pk_f32_fp8(q.y, true);
        vf2 f4 = __builtin_amdgcn_cvt_pk_f32_fp8(q.z, false);
        f[0] = f0.x; f[1] = f0.y; f[2] = f1.x; f[3] = f1.y;
        f[4] = f2.x; f[5] = f2.y; f[6] = f3.x; f[7] = f3.y;
        f[8] = f4.x; f[9] = f4.y;
    } else {
        union { u32x4 q; __half2 h[8]; } u; u.q = q;
#pragma unroll
        for (int k = 0; k < TD / 2; ++k) {
            float2 d = __half22float2(u.h[k]);
            f[2 * k] = d.x; f[2 * k + 1] = d.y;
        }
    }
}

template<int TD, bool FP8IN>
__device__ inline void scatter_edge(u32x4 q, int dl, float* acc)
{
    float f[TD];
    decode_row<TD, FP8IN>(q, f);
    float* a = acc + dl * ASTRIDE;
#pragma unroll
    for (int t = 0; t < TD; ++t) atomicAdd(&a[t], f[t]);
}

template<int TD, bool FP8IN>
__global__ __launch_bounds__(512) void round_kernel(
    const u32x4* __restrict__ in,      // [N] 16 B rows (fp16x8 or fp8x16)
    const int*   __restrict__ gh,      // scanned (bucket,chunk) offsets
    const int*   __restrict__ col,     // packed (src<<8)|dstlow, bucket-grouped
    u32x4*       __restrict__ rout,    // [N] 16 B fp8 rows
    const float* __restrict__ H,       // [TD, M]
    const float* __restrict__ Wsc, int widx,
    float*       __restrict__ facc)
{
    __shared__ float acc[256 * ASTRIDE];
    __shared__ int   shb[2];
    __shared__ float lsm[8][M];

    int b   = blockIdx.x;
    int tid = threadIdx.x;

    for (int k = tid; k < 256 * ASTRIDE; k += 512) acc[k] = 0.0f;
    if (tid == 0) {
        shb[0] = gh[b * NBLK];
        shb[1] = (b == NB - 1) ? N_EDGES : gh[(b + 1) * NBLK];
    }
    __syncthreads();
    int e0 = shb[0], e1 = shb[1];
    int e0a = (e0 + 3) & ~3;            // align for dwordx4
    if (e0a > e1) e0a = e1;
    int nvec = (e1 - e0a) >> 2;

    // head (<=3 edges)
    for (int k = e0 + tid; k < e0a; k += 512) {
        int e = __builtin_nontemporal_load(col + k);
        scatter_edge<TD, FP8IN>(in[e >> 8], e & 255, acc);
    }
    // main: 4 packed edges per lane-iter, 4 gathers in flight
    const u32x4* colv = (const u32x4*)(col + e0a);
    for (int g = tid; g < nvec; g += 512) {
        u32x4 ee = __builtin_nontemporal_load(colv + g);
        int ex = (int)ee.x, ey = (int)ee.y, ez = (int)ee.z, ew = (int)ee.w;
        u32x4 q0 = in[ex >> 8];
        u32x4 q1 = in[ey >> 8];
        u32x4 q2 = in[ez >> 8];
        u32x4 q3 = in[ew >> 8];
        scatter_edge<TD, FP8IN>(q0, ex & 255, acc);
        scatter_edge<TD, FP8IN>(q1, ey & 255, acc);
        scatter_edge<TD, FP8IN>(q2, ez & 255, acc);
        scatter_edge<TD, FP8IN>(q3, ew & 255, acc);
    }
    // tail (<=3 edges)
    for (int k = e0a + nvec * 4 + tid; k < e1; k += 512) {
        int e = __builtin_nontemporal_load(col + k);
        scatter_edge<TD, FP8IN>(in[e >> 8], e & 255, acc);
    }
    __syncthreads();

    float w = Wsc[widx];
    float sm[M];
    int i = b * 256 + tid;

    if (tid < 256 && i < N_NODES) {
        float v[TD];
        float self[TD];
        decode_row<TD, FP8IN>(in[i], self);
#pragma unroll
        for (int t = 0; t < TD; ++t) v[t] = acc[tid * ASTRIDE + t] + self[t];

        float z[M];
#pragma unroll
        for (int m = 0; m < M; ++m) {
            float a = 0.0f;
#pragma unroll
            for (int t = 0; t < TD; ++t) a += v[t] * H[t * M + m];
            z[m] = a;
        }
        float rr[M];
        float ssum = 0.0f;
#pragma unroll
        for (int m = 0; m < M; ++m) {
            rr[m] = 1.0f / (1.0f + __expf(-z[m]));
            sm[m] = __expf(rr[m] * w);            // rr*w in (0,0.2): no max shift
            ssum += sm[m];
        }
        {
            int d0 = __builtin_amdgcn_cvt_pk_fp8_f32(rr[0], rr[1], 0, false);
            d0     = __builtin_amdgcn_cvt_pk_fp8_f32(rr[2], rr[3], d0, true);
            int d1 = __builtin_amdgcn_cvt_pk_fp8_f32(rr[4], rr[5], 0, false);
            d1     = __builtin_amdgcn_cvt_pk_fp8_f32(rr[6], rr[7], d1, true);
            int d2 = __builtin_amdgcn_cvt_pk_fp8_f32(rr[8], rr[9], 0, false);
            u32x4 o = { (unsigned)d0, (unsigned)d1, (unsigned)d2, 0u };
            __builtin_nontemporal_store(o, rout + i);
        }
        float inv = 1.0f / ssum;
#pragma unroll
        for (int m = 0; m < M; ++m) sm[m] *= inv;
    } else {
#pragma unroll
        for (int m = 0; m < M; ++m) sm[m] = 0.0f;
    }

    // wave-64 shuffle reduction of the 10 softmax sums (8 waves)
#pragma unroll
    for (int m = 0; m < M; ++m) {
        float x = sm[m];
#pragma unroll
        for (int o = 32; o > 0; o >>= 1) x += __shfl_down(x, o);
        sm[m] = x;
    }
    int lane = tid & 63;
    int wv   = tid >> 6;
    if (lane == 0) {
#pragma unroll
        for (int m = 0; m < M; ++m) lsm[wv][m] = sm[m];
    }
    __syncthreads();
    if (tid < M) {
        float a = 0.0f;
#pragma unroll
        for (int k = 0; k < 8; ++k) a += lsm[k][tid];
        atomicAdd(&facc[tid], a);
    }
}

// ---------------------------------------------------------------------------
// final head: out[3] = concat(f[10], x_group@Wg[4]) @ Wm
// ---------------------------------------------------------------------------
__global__ void final_kernel(const float* __restrict__ facc,
                             const float* __restrict__ xg,
                             const float* __restrict__ Wg,
                             const float* __restrict__ Wm,
                             float* __restrict__ out)
{
    if (threadIdx.x == 0 && blockIdx.x == 0) {
        float go[4];
        for (int g = 0; g < 4; ++g) {
            float a = 0.0f;
            for (int i = 0; i < 14; ++i) a += xg[i] * Wg[i * 4 + g];
            go[g] = a;
        }
        for (int j = 0; j < 3; ++j) {
            float o = 0.0f;
            for (int k = 0; k < M; ++k) o += facc[k] * Wm[k * 3 + j];
            for (int g = 0; g < 4; ++g)  o += go[g] * Wm[(M + g) * 3 + j];
            out[j] = o;
        }
    }
}

extern "C" void kernel_launch(void* const* d_in, const int* in_sizes, int n_in,
                              void* d_out, int out_size, void* d_ws, size_t ws_size,
                              hipStream_t stream)
{
    const float* x_member = (const float*)d_in[0];
    const float* x_group  = (const float*)d_in[1];
    const int*   edge_src = (const int*)  d_in[2];
    const int*   edge_dst = (const int*)  d_in[3];
    const float* H0       = (const float*)d_in[4];
    const float* Hs       = (const float*)d_in[5];
    const float* Wsc      = (const float*)d_in[6];
    const float* Wg       = (const float*)d_in[7];
    const float* Wm       = (const float*)d_in[8];
    float* out = (float*)d_out;

    // workspace layout — 36.1 MB (passD/off deleted; gh now lives through all
    // rounds -> moved out of the r1b alias into its own region):
    //   col/ebuf : 25,600,000 B
    //   gh       :    800,768 B  (GHLEN ints)  @ 25,600,000
    //   bsum     :        784 B                @ 26,400,768
    //   xh       :  3,200,000 B  [N] fp16x8    @ 26,420,000
    //   r0b      :  3,200,000 B  [N] fp8x16    @ 29,620,000
    //   r1b      :  3,200,000 B  [N] fp8x16    @ 32,820,000
    //   facc     :         64 B                @ 36,020,000
    char* w = (char*)d_ws;
    int*    col  = (int*)w;
    int*    gh   = (int*)(w + 25600000);
    int*    bsum = gh + GHLEN;
    __half* xh   = (__half*)(w + 26420000);
    u32x4*  r0b  = (u32x4*)(w + 29620000);
    u32x4*  r1b  = (u32x4*)(w + 32820000);
    float*  facc = (float*)(w + 36020000);

    // raise dynamic-LDS cap for passC (host-side attr, graph-capture safe)
    static bool attr_done = false;
    if (!attr_done) {
        (void)hipFuncSetAttribute((const void*)passC_kernel,
                                  hipFuncAttributeMaxDynamicSharedMemorySize,
                                  PASSC_LDS_BYTES);
        attr_done = true;
    }

    (void)hipMemsetAsync(facc, 0, 64, stream);

    const int nblocks = (N_NODES + 255) / 256;    // 782

    convert_kernel<<<nblocks, 256, 0, stream>>>(x_member, xh);
    passA_kernel<<<NBLK, 1024, 0, stream>>>(edge_dst, gh);
    scan1_kernel<<<SBLOCKS, 1024, 0, stream>>>(gh, bsum);
    scan2_kernel<<<1, 256, 0, stream>>>(bsum);
    scan3_kernel<<<SBLOCKS, 1024, 0, stream>>>(gh, bsum);
    passC_kernel<<<NBLK, 1024, PASSC_LDS_BYTES, stream>>>(edge_src, edge_dst, gh, col);

    round_kernel<T, false><<<NB, 512, 0, stream>>>((const u32x4*)xh, gh, col, r0b, H0,             Wsc, 0, facc);
    round_kernel<M, true ><<<NB, 512, 0, stream>>>(r0b,              gh, col, r1b, Hs + 0 * M * M, Wsc, 1, facc);
    round_kernel<M, true ><<<NB, 512, 0, stream>>>(r1b,              gh, col, r0b, Hs + 1 * M * M, Wsc, 2, facc);
    round_kernel<M, true ><<<NB, 512, 0, stream>>>(r0b,              gh, col, r1b, Hs + 2 * M * M, Wsc, 3, facc);

    final_kernel<<<1, 64, 0, stream>>>(facc, x_group, Wg, Wm, out);
}

// Round 5
// 403.541 us; speedup vs baseline: 4.1961x; 4.1961x over previous
//
#include <hip/hip_runtime.h>
#include <hip/hip_fp16.h>
#include <math.h>

#define N_NODES 200000
#define N_EDGES 6400000
#define T 6
#define M 10

// CSR build configuration: 256-node buckets, chunked counting sort.
#define NB    782            // ceil(200000/256) buckets (dst>>8)
#define NBLK  256            // edge chunks == CU count
#define CH    25000          // edges per chunk (256*25000 = 6.4M exact)
#define GHLEN (NB * NBLK)    // 200192
#define CAP   14336          // max edges per bucket (mean 8186, sigma 90 -> 68 sigma margin)

#define SBLOCKS 196          // ceil(GHLEN/1024) scan blocks

// passC dynamic LDS: edge array (CH) + cnt/ls/lcur/gs (4*NB) + scan buf (1024)
#define PASSC_LDS_INTS  (CH + 4 * NB + 1024)
#define PASSC_LDS_BYTES (PASSC_LDS_INTS * 4)   // 116,608 B < 160 KiB/CU

// round kernel: staged col ints per bucket (36 KB). Bucket size is
// mean 8186, sigma 90 -> max over 782 buckets ~ 8490. 9216 = +11 sigma;
// a global-memory guard path covers the (never-seen) overflow case.
#define LCAP 9216
#define VSTRIDE 11           // vpart row stride: gcd(11,32)=1 -> conflict-free

typedef __attribute__((ext_vector_type(2))) float vf2;
typedef __attribute__((ext_vector_type(4))) unsigned int u32x4;

// ---------------------------------------------------------------------------
// convert x_member [N,6] fp32 -> xh [N,8] fp16 (zero-padded), 16 B rows.
// ---------------------------------------------------------------------------
__global__ __launch_bounds__(256) void convert_kernel(
    const float* __restrict__ x, __half* __restrict__ xh)
{
    int i = blockIdx.x * 256 + threadIdx.x;
    if (i >= N_NODES) return;
    const vf2* p = (const vf2*)(x + (size_t)i * 6);   // rows 24B -> 8B aligned
    vf2 a = __builtin_nontemporal_load(p);
    vf2 b = __builtin_nontemporal_load(p + 1);
    vf2 c = __builtin_nontemporal_load(p + 2);
    union { __half2 h[4]; u32x4 q; } u;
    u.h[0] = __floats2half2_rn(a.x, a.y);
    u.h[1] = __floats2half2_rn(b.x, b.y);
    u.h[2] = __floats2half2_rn(c.x, c.y);
    u.h[3] = __floats2half2_rn(0.f, 0.f);
    __builtin_nontemporal_store(u.q, (u32x4*)(xh + (size_t)i * 8));
}

// ---------------------------------------------------------------------------
// Pass A: per-chunk bucket histogram -> gh[bucket*NBLK + chunk]
// ---------------------------------------------------------------------------
__global__ __launch_bounds__(1024) void passA_kernel(
    const int* __restrict__ dst, int* __restrict__ gh)
{
    __shared__ int lh[NB];
    int g = blockIdx.x;
    for (int t = threadIdx.x; t < NB; t += 1024) lh[t] = 0;
    __syncthreads();
    int base = g * CH;
    int end  = base + CH; if (end > N_EDGES) end = N_EDGES;
    for (int e = base + threadIdx.x; e < end; e += 1024)
        atomicAdd(&lh[__builtin_nontemporal_load(dst + e) >> 8], 1);
    __syncthreads();
    for (int t = threadIdx.x; t < NB; t += 1024) gh[t * NBLK + g] = lh[t];
}

// ---------------------------------------------------------------------------
// Hierarchical exclusive scan of gh[GHLEN]
// ---------------------------------------------------------------------------
__global__ __launch_bounds__(1024) void scan1_kernel(
    int* __restrict__ gh, int* __restrict__ bsum)
{
    __shared__ int sbuf[1024];
    int tid = threadIdx.x;
    int t   = blockIdx.x * 1024 + tid;
    int v   = (t < GHLEN) ? gh[t] : 0;
    sbuf[tid] = v;
    __syncthreads();
    for (int d = 1; d < 1024; d <<= 1) {
        int u = (tid >= d) ? sbuf[tid - d] : 0;
        __syncthreads();
        sbuf[tid] += u;
        __syncthreads();
    }
    if (t < GHLEN) gh[t] = sbuf[tid] - v;           // local exclusive
    if (tid == 1023) bsum[blockIdx.x] = sbuf[1023]; // block total
}

__global__ __launch_bounds__(256) void scan2_kernel(int* __restrict__ bsum)
{
    __shared__ int sbuf[256];
    int tid = threadIdx.x;
    int v = (tid < SBLOCKS) ? bsum[tid] : 0;
    sbuf[tid] = v;
    __syncthreads();
    for (int d = 1; d < 256; d <<= 1) {
        int u = (tid >= d) ? sbuf[tid - d] : 0;
        __syncthreads();
        sbuf[tid] += u;
        __syncthreads();
    }
    if (tid < SBLOCKS) bsum[tid] = sbuf[tid] - v;   // exclusive
}

__global__ __launch_bounds__(1024) void scan3_kernel(
    int* __restrict__ gh, const int* __restrict__ bsum)
{
    int t = blockIdx.x * 1024 + threadIdx.x;
    if (t < GHLEN) gh[t] += bsum[blockIdx.x];
}

// ---------------------------------------------------------------------------
// Pass C: counting-sort the whole chunk INSIDE LDS, then copy each
// (bucket,chunk) segment out as a contiguous per-wave burst (full-line,
// write-once; scattered 4 B stores cost 5.9x write amp at HBM).
// ---------------------------------------------------------------------------
__global__ __launch_bounds__(1024) void passC_kernel(
    const int* __restrict__ src, const int* __restrict__ dst,
    const int* __restrict__ gh, int* __restrict__ ebuf)
{
    extern __shared__ int dyn[];
    int* earr = dyn;             // [CH]  bucket-sorted packed edges
    int* cnt  = dyn + CH;        // [NB]  edges of bucket b in this chunk
    int* ls   = cnt + NB;        // [NB]  local exclusive start
    int* lcur = ls + NB;         // [NB]  scatter cursor
    int* gs   = lcur + NB;       // [NB]  global segment start
    int* sbuf = gs + NB;         // [1024] scan temp

    int g   = blockIdx.x;
    int tid = threadIdx.x;

    // per-bucket global start + count for this chunk, from scanned gh
    for (int b = tid; b < NB; b += 1024) {
        int idx = b * NBLK + g;
        int s0  = gh[idx];
        int s1  = (idx + 1 < GHLEN) ? gh[idx + 1] : N_EDGES;
        gs[b]  = s0;
        cnt[b] = s1 - s0;
    }
    __syncthreads();

    // exclusive scan of cnt -> ls (NB=782 <= 1024, single pass)
    int v = (tid < NB) ? cnt[tid] : 0;
    sbuf[tid] = v;
    __syncthreads();
    for (int d = 1; d < 1024; d <<= 1) {
        int u = (tid >= d) ? sbuf[tid - d] : 0;
        __syncthreads();
        sbuf[tid] += u;
        __syncthreads();
    }
    if (tid < NB) { int e0 = sbuf[tid] - v; ls[tid] = e0; lcur[tid] = e0; }
    __syncthreads();

    // scatter chunk edges into LDS, bucket-grouped (LDS atomics only)
    int base = g * CH;
    for (int e = base + tid; e < base + CH; e += 1024) {
        int s = __builtin_nontemporal_load(src + e);
        int d = __builtin_nontemporal_load(dst + e);
        int b = d >> 8;
        int p = atomicAdd(&lcur[b], 1);
        earr[p] = (s << 8) | (d & 255);
    }
    __syncthreads();

    // coalesced copy-out: one wave per bucket segment (mean 32 edges = 128 B)
    int wv = tid >> 6, lane = tid & 63;
    for (int b = wv; b < NB; b += 16) {
        int bl = ls[b], bg = gs[b], c = cnt[b];
        for (int o = lane; o < c; o += 64)
            ebuf[bg + o] = earr[bl + o];   // normal store: L2 merges the
    }                                      // chunk-boundary-shared lines
}

// ---------------------------------------------------------------------------
// Pass D: per-bucket counting sort, IN PLACE (col aliases ebuf).
// v2: 512 threads. LDS is 59 KB -> 2 blocks/CU; at 256 threads that was
// only 8 waves/CU (15% occ, latency-exposed). 512 threads -> 16 waves/CU.
// Scan phase runs on first 256 lanes with uniform barriers.
// ---------------------------------------------------------------------------
__global__ __launch_bounds__(512) void passD_kernel(
    const int* __restrict__ gh, int* __restrict__ col, int* __restrict__ off)
{
    __shared__ int earr[CAP];
    __shared__ int hist[256];
    __shared__ int incl[256];
    int b   = blockIdx.x;
    int tid = threadIdx.x;
    int ebase = gh[b * NBLK];
    int eend  = (b == NB - 1) ? N_EDGES : gh[(b + 1) * NBLK];
    int n = eend - ebase;
    if (n > CAP) n = CAP;   // 68-sigma margin; never triggers for this input
    for (int k = tid; k < n; k += 512)
        earr[k] = __builtin_nontemporal_load(col + ebase + k);
    if (tid < 256) hist[tid] = 0;
    __syncthreads();
    for (int k = tid; k < n; k += 512) atomicAdd(&hist[earr[k] & 255], 1);
    __syncthreads();
    int t = tid;
    int h = 0;
    if (t < 256) { h = hist[t]; incl[t] = h; }
    __syncthreads();
    for (int d = 1; d < 256; d <<= 1) {
        int v = (t < 256 && t >= d) ? incl[t - d] : 0;
        __syncthreads();
        if (t < 256) incl[t] += v;
        __syncthreads();
    }
    if (t < 256) {
        int node = b * 256 + t;
        if (node < N_NODES) off[node] = ebase + incl[t];
        hist[t] = incl[t] - h;                   // exclusive cursor
    }
    __syncthreads();
    for (int k = tid; k < n; k += 512) {
        int e = earr[k];
        int p = atomicAdd(&hist[e & 255], 1);    // LDS atomic
        col[ebase + p] = e >> 8;                 // normal store (L2 coalesces)
    }
}

// ---------------------------------------------------------------------------
// round, v4: block == bucket (256 nodes), 512 threads = 2 threads/node.
// Thread pair (nid, nid+256) each walks half the node's segment (8-deep
// gather pipeline each); halves merge through vpart[256][11] in LDS.
//
// Why: r3's 256-thread version sat at 27% occupancy (grid-limited) with the
// random 16 B gather latency-exposed (~5.4 cyc/txn effective vs ~1
// achievable). 512 threads -> 24 waves/CU (75%) and halves each thread's
// serial chain. col stays LDS-staged (r3: FETCH 69->25.6 MB, confirmed).
// NOTE r4 lesson: LDS float atomics serialize (~260 cyc each, CAS-loop
// path) -- partials must merge via plain stores + barrier, never atomics.
// ---------------------------------------------------------------------------
template<int TD, bool FP8IN>
__device__ inline void accum_row(u32x4 q, float* v)
{
    if (FP8IN) {
        vf2 f0 = __builtin_amdgcn_cvt_pk_f32_fp8(q.x, false);
        vf2 f1 = __builtin_amdgcn_cvt_pk_f32_fp8(q.x, true);
        vf2 f2 = __builtin_amdgcn_cvt_pk_f32_fp8(q.y, false);
        vf2 f3 = __builtin_amdgcn_cvt_pk_f32_fp8(q.y, true);
        vf2 f4 = __builtin_amdgcn_cvt_pk_f32_fp8(q.z, false);
        v[0] += f0.x; v[1] += f0.y; v[2] += f1.x; v[3] += f1.y;
        v[4] += f2.x; v[5] += f2.y; v[6] += f3.x; v[7] += f3.y;
        v[8] += f4.x; v[9] += f4.y;
    } else {
        union { u32x4 q; __half2 h[8]; } u; u.q = q;
#pragma unroll
        for (int k = 0; k < TD / 2; ++k) {
            float2 f = __half22float2(u.h[k]);
            v[2 * k] += f.x; v[2 * k + 1] += f.y;
        }
    }
}

template<int TD, bool FP8IN>
__global__ __launch_bounds__(512) void round_kernel(
    const u32x4* __restrict__ in,      // [N] 16 B rows (fp16x8 or fp8x16)
    const int*   __restrict__ off,
    const int*   __restrict__ col,
    u32x4*       __restrict__ rout,    // [N] 16 B fp8 rows
    const float* __restrict__ H,       // [TD, M]
    const float* __restrict__ Wsc, int widx,
    float*       __restrict__ facc)
{
    __shared__ int   lcol[LCAP];
    __shared__ int   shb[2];
    __shared__ float vpart[256][VSTRIDE];
    __shared__ float lsm[8][M];

    int b    = blockIdx.x;
    int tid  = threadIdx.x;
    int nid  = tid & 255;              // node slot within bucket
    int half = tid >> 8;               // 0 or 1: which half of the segment
    int i    = b * 256 + nid;

    if (tid == 0) {
        shb[0] = (b == 0) ? 0 : __builtin_nontemporal_load(off + b * 256 - 1);
        int lastnode = (b * 256 + 256 <= N_NODES) ? (b * 256 + 255) : (N_NODES - 1);
        shb[1] = __builtin_nontemporal_load(off + lastnode);
    }
    __syncthreads();
    int ebase  = shb[0];
    int nseg   = shb[1] - ebase;
    int nstage = nseg < LCAP ? nseg : LCAP;
    for (int k = tid; k < nstage; k += 512)
        lcol[k] = __builtin_nontemporal_load(col + ebase + k);   // coalesced
    __syncthreads();

    float w = Wsc[widx];
    float sm[M];
    bool have = (i < N_NODES);

    float v[TD];
#pragma unroll
    for (int t = 0; t < TD; ++t) v[t] = 0.0f;

    if (have) {
        int gstart = (i == 0) ? 0 : __builtin_nontemporal_load(off + i - 1);
        int gend   = __builtin_nontemporal_load(off + i);
        int js = gstart - ebase;
        int je = gend   - ebase;
        int jm = js + ((je - js + 1) >> 1);
        int j0 = half ? jm : js;
        int j1 = half ? je : jm;

        if (half == 0) accum_row<TD, FP8IN>(in[i], v);   // self term

        if (je <= nstage) {                  // fast path: col in LDS
            int j = j0;
            for (; j + 8 <= j1; j += 8) {    // 8 outstanding gathers/lane
                int s0 = lcol[j];
                int s1 = lcol[j + 1];
                int s2 = lcol[j + 2];
                int s3 = lcol[j + 3];
                int s4 = lcol[j + 4];
                int s5 = lcol[j + 5];
                int s6 = lcol[j + 6];
                int s7 = lcol[j + 7];
                u32x4 q0 = in[s0], q1 = in[s1], q2 = in[s2], q3 = in[s3];
                u32x4 q4 = in[s4], q5 = in[s5], q6 = in[s6], q7 = in[s7];
                accum_row<TD, FP8IN>(q0, v);
                accum_row<TD, FP8IN>(q1, v);
                accum_row<TD, FP8IN>(q2, v);
                accum_row<TD, FP8IN>(q3, v);
                accum_row<TD, FP8IN>(q4, v);
                accum_row<TD, FP8IN>(q5, v);
                accum_row<TD, FP8IN>(q6, v);
                accum_row<TD, FP8IN>(q7, v);
            }
            for (; j < j1; ++j)
                accum_row<TD, FP8IN>(in[lcol[j]], v);
        } else {                             // overflow guard (never hit)
            for (int j = j0; j < j1; ++j)
                accum_row<TD, FP8IN>(in[__builtin_nontemporal_load(col + ebase + j)], v);
        }
    }

    // merge halves: half1 deposits partial, half0 consumes (plain stores!)
    if (half == 1) {
#pragma unroll
        for (int t = 0; t < TD; ++t) vpart[nid][t] = v[t];
    }
    __syncthreads();

    if (have && half == 0) {
#pragma unroll
        for (int t = 0; t < TD; ++t) v[t] += vpart[nid][t];

        float z[M];
#pragma unroll
        for (int m = 0; m < M; ++m) {
            float acc = 0.0f;
#pragma unroll
            for (int t = 0; t < TD; ++t) acc += v[t] * H[t * M + m];
            z[m] = acc;
        }
        float rr[M];
        float ssum = 0.0f;
#pragma unroll
        for (int m = 0; m < M; ++m) {
            rr[m] = 1.0f / (1.0f + __expf(-z[m]));
            sm[m] = __expf(rr[m] * w);            // rr*w in (0,0.2): no max shift
            ssum += sm[m];
        }
        {
            int d0 = __builtin_amdgcn_cvt_pk_fp8_f32(rr[0], rr[1], 0, false);
            d0     = __builtin_amdgcn_cvt_pk_fp8_f32(rr[2], rr[3], d0, true);
            int d1 = __builtin_amdgcn_cvt_pk_fp8_f32(rr[4], rr[5], 0, false);
            d1     = __builtin_amdgcn_cvt_pk_fp8_f32(rr[6], rr[7], d1, true);
            int d2 = __builtin_amdgcn_cvt_pk_fp8_f32(rr[8], rr[9], 0, false);
            u32x4 o = { (unsigned)d0, (unsigned)d1, (unsigned)d2, 0u };
            __builtin_nontemporal_store(o, rout + i);
        }
        float inv = 1.0f / ssum;
#pragma unroll
        for (int m = 0; m < M; ++m) sm[m] *= inv;
    } else {
#pragma unroll
        for (int m = 0; m < M; ++m) sm[m] = 0.0f;
    }

    // wave-64 shuffle reduction of the 10 softmax sums (8 waves)
#pragma unroll
    for (int m = 0; m < M; ++m) {
        float x = sm[m];
#pragma unroll
        for (int o = 32; o > 0; o >>= 1) x += __shfl_down(x, o);
        sm[m] = x;
    }
    int lane = tid & 63;
    int wv   = tid >> 6;
    if (lane == 0) {
#pragma unroll
        for (int m = 0; m < M; ++m) lsm[wv][m] = sm[m];
    }
    __syncthreads();
    if (tid < M) {
        float a = 0.0f;
#pragma unroll
        for (int k = 0; k < 8; ++k) a += lsm[k][tid];
        atomicAdd(&facc[tid], a);
    }
}

// ---------------------------------------------------------------------------
// final head: out[3] = concat(f[10], x_group@Wg[4]) @ Wm
// ---------------------------------------------------------------------------
__global__ void final_kernel(const float* __restrict__ facc,
                             const float* __restrict__ xg,
                             const float* __restrict__ Wg,
                             const float* __restrict__ Wm,
                             float* __restrict__ out)
{
    if (threadIdx.x == 0 && blockIdx.x == 0) {
        float go[4];
        for (int g = 0; g < 4; ++g) {
            float a = 0.0f;
            for (int i = 0; i < 14; ++i) a += xg[i] * Wg[i * 4 + g];
            go[g] = a;
        }
        for (int j = 0; j < 3; ++j) {
            float o = 0.0f;
            for (int k = 0; k < M; ++k) o += facc[k] * Wm[k * 3 + j];
            for (int g = 0; g < 4; ++g)  o += go[g] * Wm[(M + g) * 3 + j];
            out[j] = o;
        }
    }
}

extern "C" void kernel_launch(void* const* d_in, const int* in_sizes, int n_in,
                              void* d_out, int out_size, void* d_ws, size_t ws_size,
                              hipStream_t stream)
{
    const float* x_member = (const float*)d_in[0];
    const float* x_group  = (const float*)d_in[1];
    const int*   edge_src = (const int*)  d_in[2];
    const int*   edge_dst = (const int*)  d_in[3];
    const float* H0       = (const float*)d_in[4];
    const float* Hs       = (const float*)d_in[5];
    const float* Wsc      = (const float*)d_in[6];
    const float* Wg       = (const float*)d_in[7];
    const float* Wm       = (const float*)d_in[8];
    float* out = (float*)d_out;

    // workspace layout — 36.8 MB (r3 layout):
    //   col/ebuf : 25,600,000 B   (in-place counting sort)
    //   off      :    800,000 B
    //   xh       :  3,200,000 B   [N] fp16x8, 16 B rows
    //   r0b      :  3,200,000 B   [N] fp8x16, 16 B rows
    //   r1b      :  3,200,000 B   [N] fp8x16 (gh[GHLEN]+bsum alias its head:
    //              dead after passD; r1b first written in round 1)
    //   facc     :         64 B
    char* w = (char*)d_ws;
    int*    col  = (int*)w;
    int*    off  = (int*)(w + 25600000);
    __half* xh   = (__half*)(w + 26400000);
    u32x4*  r0b  = (u32x4*)(w + 29600000);
    u32x4*  r1b  = (u32x4*)(w + 32800000);
    int*    gh   = (int*)(w + 32800000);          // aliases r1b
    int*    bsum = gh + GHLEN;                    // also in r1b region
    float*  facc = (float*)(w + 36000000);

    // raise dynamic-LDS cap for passC (host-side attr, graph-capture safe)
    static bool attr_done = false;
    if (!attr_done) {
        (void)hipFuncSetAttribute((const void*)passC_kernel,
                                  hipFuncAttributeMaxDynamicSharedMemorySize,
                                  PASSC_LDS_BYTES);
        attr_done = true;
    }

    (void)hipMemsetAsync(facc, 0, 64, stream);

    const int nblocks = (N_NODES + 255) / 256;    // 782

    convert_kernel<<<nblocks, 256, 0, stream>>>(x_member, xh);
    passA_kernel<<<NBLK, 1024, 0, stream>>>(edge_dst, gh);
    scan1_kernel<<<SBLOCKS, 1024, 0, stream>>>(gh, bsum);
    scan2_kernel<<<1, 256, 0, stream>>>(bsum);
    scan3_kernel<<<SBLOCKS, 1024, 0, stream>>>(gh, bsum);
    passC_kernel<<<NBLK, 1024, PASSC_LDS_BYTES, stream>>>(edge_src, edge_dst, gh, col);
    passD_kernel<<<NB, 512, 0, stream>>>(gh, col, off);

    round_kernel<T, false><<<nblocks, 512, 0, stream>>>((const u32x4*)xh, off, col, r0b, H0,             Wsc, 0, facc);
    round_kernel<M, true ><<<nblocks, 512, 0, stream>>>(r0b,              off, col, r1b, Hs + 0 * M * M, Wsc, 1, facc);
    round_kernel<M, true ><<<nblocks, 512, 0, stream>>>(r1b,              off, col, r0b, Hs + 1 * M * M, Wsc, 2, facc);
    round_kernel<M, true ><<<nblocks, 512, 0, stream>>>(r0b,              off, col, r1b, Hs + 2 * M * M, Wsc, 3, facc);

    final_kernel<<<1, 64, 0, stream>>>(facc, x_group, Wg, Wm, out);
}

// Round 6
// 329.711 us; speedup vs baseline: 5.1357x; 1.2239x over previous
//
#include <hip/hip_runtime.h>
#include <hip/hip_fp16.h>
#include <math.h>

#define N_NODES 200000
#define N_EDGES 6400000
#define T 6
#define M 10

// CSR build configuration: 256-node buckets, chunked counting sort.
#define NB    782            // ceil(200000/256) buckets (dst>>8)
#define NBLK  256            // edge chunks == CU count
#define CH    25000          // edges per chunk (256*25000 = 6.4M exact)
#define GHLEN (NB * NBLK)    // 200192

#define SBLOCKS 196          // ceil(GHLEN/1024) scan blocks

// passC dynamic LDS: edge array (CH) + cnt/ls/lcur/gs (4*NB) + scan buf (1024)
#define PASSC_LDS_INTS  (CH + 4 * NB + 1024)
#define PASSC_LDS_BYTES (PASSC_LDS_INTS * 4)   // 116,608 B < 160 KiB/CU

#define ASTRIDE 11           // acc row stride: gcd(11,32)=1 -> uniform banks
#define QSCALE  262144.0f    // 2^18 fixed-point scale (max |sum| ~30 -> safe)
#define QINV    (1.0f / 262144.0f)

typedef __attribute__((ext_vector_type(2))) float vf2;
typedef __attribute__((ext_vector_type(4))) unsigned int u32x4;

// ---------------------------------------------------------------------------
// convert x_member [N,6] fp32 -> xh [N,8] fp16 (zero-padded), 16 B rows.
// ---------------------------------------------------------------------------
__global__ __launch_bounds__(256) void convert_kernel(
    const float* __restrict__ x, __half* __restrict__ xh)
{
    int i = blockIdx.x * 256 + threadIdx.x;
    if (i >= N_NODES) return;
    const vf2* p = (const vf2*)(x + (size_t)i * 6);   // rows 24B -> 8B aligned
    vf2 a = __builtin_nontemporal_load(p);
    vf2 b = __builtin_nontemporal_load(p + 1);
    vf2 c = __builtin_nontemporal_load(p + 2);
    union { __half2 h[4]; u32x4 q; } u;
    u.h[0] = __floats2half2_rn(a.x, a.y);
    u.h[1] = __floats2half2_rn(b.x, b.y);
    u.h[2] = __floats2half2_rn(c.x, c.y);
    u.h[3] = __floats2half2_rn(0.f, 0.f);
    __builtin_nontemporal_store(u.q, (u32x4*)(xh + (size_t)i * 8));
}

// ---------------------------------------------------------------------------
// Pass A: per-chunk bucket histogram -> gh[bucket*NBLK + chunk]
// ---------------------------------------------------------------------------
__global__ __launch_bounds__(1024) void passA_kernel(
    const int* __restrict__ dst, int* __restrict__ gh)
{
    __shared__ int lh[NB];
    int g = blockIdx.x;
    for (int t = threadIdx.x; t < NB; t += 1024) lh[t] = 0;
    __syncthreads();
    int base = g * CH;
    int end  = base + CH; if (end > N_EDGES) end = N_EDGES;
    for (int e = base + threadIdx.x; e < end; e += 1024)
        atomicAdd(&lh[__builtin_nontemporal_load(dst + e) >> 8], 1);
    __syncthreads();
    for (int t = threadIdx.x; t < NB; t += 1024) gh[t * NBLK + g] = lh[t];
}

// ---------------------------------------------------------------------------
// Hierarchical exclusive scan of gh[GHLEN]
// ---------------------------------------------------------------------------
__global__ __launch_bounds__(1024) void scan1_kernel(
    int* __restrict__ gh, int* __restrict__ bsum)
{
    __shared__ int sbuf[1024];
    int tid = threadIdx.x;
    int t   = blockIdx.x * 1024 + tid;
    int v   = (t < GHLEN) ? gh[t] : 0;
    sbuf[tid] = v;
    __syncthreads();
    for (int d = 1; d < 1024; d <<= 1) {
        int u = (tid >= d) ? sbuf[tid - d] : 0;
        __syncthreads();
        sbuf[tid] += u;
        __syncthreads();
    }
    if (t < GHLEN) gh[t] = sbuf[tid] - v;           // local exclusive
    if (tid == 1023) bsum[blockIdx.x] = sbuf[1023]; // block total
}

__global__ __launch_bounds__(256) void scan2_kernel(int* __restrict__ bsum)
{
    __shared__ int sbuf[256];
    int tid = threadIdx.x;
    int v = (tid < SBLOCKS) ? bsum[tid] : 0;
    sbuf[tid] = v;
    __syncthreads();
    for (int d = 1; d < 256; d <<= 1) {
        int u = (tid >= d) ? sbuf[tid - d] : 0;
        __syncthreads();
        sbuf[tid] += u;
        __syncthreads();
    }
    if (tid < SBLOCKS) bsum[tid] = sbuf[tid] - v;   // exclusive
}

__global__ __launch_bounds__(1024) void scan3_kernel(
    int* __restrict__ gh, const int* __restrict__ bsum)
{
    int t = blockIdx.x * 1024 + threadIdx.x;
    if (t < GHLEN) gh[t] += bsum[blockIdx.x];
}

// ---------------------------------------------------------------------------
// Pass C: counting-sort the whole chunk INSIDE LDS, then copy each
// (bucket,chunk) segment out as a contiguous per-wave burst (full-line,
// write-once; scattered 4 B stores cost 5.9x write amp at HBM).
// ---------------------------------------------------------------------------
__global__ __launch_bounds__(1024) void passC_kernel(
    const int* __restrict__ src, const int* __restrict__ dst,
    const int* __restrict__ gh, int* __restrict__ ebuf)
{
    extern __shared__ int dyn[];
    int* earr = dyn;             // [CH]  bucket-sorted packed edges
    int* cnt  = dyn + CH;        // [NB]  edges of bucket b in this chunk
    int* ls   = cnt + NB;        // [NB]  local exclusive start
    int* lcur = ls + NB;         // [NB]  scatter cursor
    int* gs   = lcur + NB;       // [NB]  global segment start
    int* sbuf = gs + NB;         // [1024] scan temp

    int g   = blockIdx.x;
    int tid = threadIdx.x;

    // per-bucket global start + count for this chunk, from scanned gh
    for (int b = tid; b < NB; b += 1024) {
        int idx = b * NBLK + g;
        int s0  = gh[idx];
        int s1  = (idx + 1 < GHLEN) ? gh[idx + 1] : N_EDGES;
        gs[b]  = s0;
        cnt[b] = s1 - s0;
    }
    __syncthreads();

    // exclusive scan of cnt -> ls (NB=782 <= 1024, single pass)
    int v = (tid < NB) ? cnt[tid] : 0;
    sbuf[tid] = v;
    __syncthreads();
    for (int d = 1; d < 1024; d <<= 1) {
        int u = (tid >= d) ? sbuf[tid - d] : 0;
        __syncthreads();
        sbuf[tid] += u;
        __syncthreads();
    }
    if (tid < NB) { int e0 = sbuf[tid] - v; ls[tid] = e0; lcur[tid] = e0; }
    __syncthreads();

    // scatter chunk edges into LDS, bucket-grouped (LDS atomics only)
    int base = g * CH;
    for (int e = base + tid; e < base + CH; e += 1024) {
        int s = __builtin_nontemporal_load(src + e);
        int d = __builtin_nontemporal_load(dst + e);
        int b = d >> 8;
        int p = atomicAdd(&lcur[b], 1);
        earr[p] = (s << 8) | (d & 255);
    }
    __syncthreads();

    // coalesced copy-out: one wave per bucket segment (mean 32 edges = 128 B)
    int wv = tid >> 6, lane = tid & 63;
    for (int b = wv; b < NB; b += 16) {
        int bl = ls[b], bg = gs[b], c = cnt[b];
        for (int o = lane; o < c; o += 64)
            ebuf[bg + o] = earr[bl + o];   // normal store: L2 merges the
    }                                      // chunk-boundary-shared lines
}

// ---------------------------------------------------------------------------
// round, v5: scatter-accumulate into per-dst LDS accumulators, INT fixed-point.
//
// Rounds are at a per-CU gather-txn floor (~25000 random 16B gathers/CU x
// ~5.5 cyc = ~57 us; r3/r5 both measured it, occupancy-insensitive). So the
// win here is DELETING passD (~30-55 us): segment-sum is commutative, so
// bucket-grouped edges (passC output) suffice if we scatter into acc[dst].
//
// r4 lesson (431 us failure): the accumulator was passed as a float* param
// -> generic/flat atomic path (zero SQ_LDS_BANK_CONFLICT proved the DS pipe
// was never used). passA/C/D's fast pattern = atomicAdd on a DIRECTLY
// indexed __shared__ int array -> native ds_add_u32 fire-and-forget. So:
// int fixed-point (scale 2^18; |sum|<=~30 -> no overflow; quant err 4e-6
// << fp8 storage noise), atomics inline on the in-scope shared array.
// ASTRIDE=11: dl*11+t mod 32 uniform over random dl -> ~2-way banks (free).
// ---------------------------------------------------------------------------
template<int TD, bool FP8IN>
__device__ inline void decode_row(u32x4 q, float* f)
{
    if (FP8IN) {
        vf2 f0 = __builtin_amdgcn_cvt_pk_f32_fp8(q.x, false);
        vf2 f1 = __builtin_amdgcn_cvt_pk_f32_fp8(q.x, true);
        vf2 f2 = __builtin_amdgcn_cvt_pk_f32_fp8(q.y, false);
        vf2 f3 = __builtin_amdgcn_cvt_pk_f32_fp8(q.y, true);
        vf2 f4 = __builtin_amdgcn_cvt_pk_f32_fp8(q.z, false);
        f[0] = f0.x; f[1] = f0.y; f[2] = f1.x; f[3] = f1.y;
        f[4] = f2.x; f[5] = f2.y; f[6] = f3.x; f[7] = f3.y;
        f[8] = f4.x; f[9] = f4.y;
    } else {
        union { u32x4 q; __half2 h[8]; } u; u.q = q;
#pragma unroll
        for (int k = 0; k < TD / 2; ++k) {
            float2 d = __half22float2(u.h[k]);
            f[2 * k] = d.x; f[2 * k + 1] = d.y;
        }
    }
}

template<int TD, bool FP8IN>
__global__ __launch_bounds__(512) void round_kernel(
    const u32x4* __restrict__ in,      // [N] 16 B rows (fp16x8 or fp8x16)
    const int*   __restrict__ gh,      // scanned (bucket,chunk) offsets
    const int*   __restrict__ col,     // packed (src<<8)|dstlow, bucket-grouped
    u32x4*       __restrict__ rout,    // [N] 16 B fp8 rows
    const float* __restrict__ H,       // [TD, M]
    const float* __restrict__ Wsc, int widx,
    float*       __restrict__ facc)
{
    __shared__ int   qacc[256 * ASTRIDE];
    __shared__ int   shb[2];
    __shared__ float lsm[8][M];

    int b   = blockIdx.x;
    int tid = threadIdx.x;

    for (int k = tid; k < 256 * ASTRIDE; k += 512) qacc[k] = 0;
    if (tid == 0) {
        shb[0] = gh[b * NBLK];
        shb[1] = (b == NB - 1) ? N_EDGES : gh[(b + 1) * NBLK];
    }
    __syncthreads();
    int e0 = shb[0], e1 = shb[1];
    int e0a = (e0 + 3) & ~3;            // align for dwordx4
    if (e0a > e1) e0a = e1;
    int nvec = (e1 - e0a) >> 2;

    // head (<=3 edges)
    for (int k = e0 + tid; k < e0a; k += 512) {
        int e = __builtin_nontemporal_load(col + k);
        float f[TD]; decode_row<TD, FP8IN>(in[e >> 8], f);
        int a0 = (e & 255) * ASTRIDE;
#pragma unroll
        for (int t = 0; t < TD; ++t)
            atomicAdd(&qacc[a0 + t], __float2int_rn(f[t] * QSCALE));
    }
    // main: 4 packed edges per lane-iter, 4 gathers in flight
    const u32x4* colv = (const u32x4*)(col + e0a);
    for (int g = tid; g < nvec; g += 512) {
        u32x4 ee = __builtin_nontemporal_load(colv + g);
        int ex = (int)ee.x, ey = (int)ee.y, ez = (int)ee.z, ew = (int)ee.w;
        u32x4 q0 = in[ex >> 8];
        u32x4 q1 = in[ey >> 8];
        u32x4 q2 = in[ez >> 8];
        u32x4 q3 = in[ew >> 8];
        float f0[TD], f1[TD], f2[TD], f3[TD];
        decode_row<TD, FP8IN>(q0, f0);
        decode_row<TD, FP8IN>(q1, f1);
        decode_row<TD, FP8IN>(q2, f2);
        decode_row<TD, FP8IN>(q3, f3);
        int a0 = (ex & 255) * ASTRIDE;
        int a1 = (ey & 255) * ASTRIDE;
        int a2 = (ez & 255) * ASTRIDE;
        int a3 = (ew & 255) * ASTRIDE;
#pragma unroll
        for (int t = 0; t < TD; ++t)
            atomicAdd(&qacc[a0 + t], __float2int_rn(f0[t] * QSCALE));
#pragma unroll
        for (int t = 0; t < TD; ++t)
            atomicAdd(&qacc[a1 + t], __float2int_rn(f1[t] * QSCALE));
#pragma unroll
        for (int t = 0; t < TD; ++t)
            atomicAdd(&qacc[a2 + t], __float2int_rn(f2[t] * QSCALE));
#pragma unroll
        for (int t = 0; t < TD; ++t)
            atomicAdd(&qacc[a3 + t], __float2int_rn(f3[t] * QSCALE));
    }
    // tail (<=3 edges)
    for (int k = e0a + nvec * 4 + tid; k < e1; k += 512) {
        int e = __builtin_nontemporal_load(col + k);
        float f[TD]; decode_row<TD, FP8IN>(in[e >> 8], f);
        int a0 = (e & 255) * ASTRIDE;
#pragma unroll
        for (int t = 0; t < TD; ++t)
            atomicAdd(&qacc[a0 + t], __float2int_rn(f[t] * QSCALE));
    }
    __syncthreads();

    float w = Wsc[widx];
    float sm[M];
    int i = b * 256 + tid;

    if (tid < 256 && i < N_NODES) {
        float self[TD];
        decode_row<TD, FP8IN>(in[i], self);
        float v[TD];
#pragma unroll
        for (int t = 0; t < TD; ++t)
            v[t] = (float)qacc[tid * ASTRIDE + t] * QINV + self[t];

        float z[M];
#pragma unroll
        for (int m = 0; m < M; ++m) {
            float a = 0.0f;
#pragma unroll
            for (int t = 0; t < TD; ++t) a += v[t] * H[t * M + m];
            z[m] = a;
        }
        float rr[M];
        float ssum = 0.0f;
#pragma unroll
        for (int m = 0; m < M; ++m) {
            rr[m] = 1.0f / (1.0f + __expf(-z[m]));
            sm[m] = __expf(rr[m] * w);            // rr*w in (0,0.2): no max shift
            ssum += sm[m];
        }
        {
            int d0 = __builtin_amdgcn_cvt_pk_fp8_f32(rr[0], rr[1], 0, false);
            d0     = __builtin_amdgcn_cvt_pk_fp8_f32(rr[2], rr[3], d0, true);
            int d1 = __builtin_amdgcn_cvt_pk_fp8_f32(rr[4], rr[5], 0, false);
            d1     = __builtin_amdgcn_cvt_pk_fp8_f32(rr[6], rr[7], d1, true);
            int d2 = __builtin_amdgcn_cvt_pk_fp8_f32(rr[8], rr[9], 0, false);
            u32x4 o = { (unsigned)d0, (unsigned)d1, (unsigned)d2, 0u };
            __builtin_nontemporal_store(o, rout + i);
        }
        float inv = 1.0f / ssum;
#pragma unroll
        for (int m = 0; m < M; ++m) sm[m] *= inv;
    } else {
#pragma unroll
        for (int m = 0; m < M; ++m) sm[m] = 0.0f;
    }

    // wave-64 shuffle reduction of the 10 softmax sums (8 waves)
#pragma unroll
    for (int m = 0; m < M; ++m) {
        float x = sm[m];
#pragma unroll
        for (int o = 32; o > 0; o >>= 1) x += __shfl_down(x, o);
        sm[m] = x;
    }
    int lane = tid & 63;
    int wv   = tid >> 6;
    if (lane == 0) {
#pragma unroll
        for (int m = 0; m < M; ++m) lsm[wv][m] = sm[m];
    }
    __syncthreads();
    if (tid < M) {
        float a = 0.0f;
#pragma unroll
        for (int k = 0; k < 8; ++k) a += lsm[k][tid];
        atomicAdd(&facc[tid], a);
    }
}

// ---------------------------------------------------------------------------
// final head: out[3] = concat(f[10], x_group@Wg[4]) @ Wm
// ---------------------------------------------------------------------------
__global__ void final_kernel(const float* __restrict__ facc,
                             const float* __restrict__ xg,
                             const float* __restrict__ Wg,
                             const float* __restrict__ Wm,
                             float* __restrict__ out)
{
    if (threadIdx.x == 0 && blockIdx.x == 0) {
        float go[4];
        for (int g = 0; g < 4; ++g) {
            float a = 0.0f;
            for (int i = 0; i < 14; ++i) a += xg[i] * Wg[i * 4 + g];
            go[g] = a;
        }
        for (int j = 0; j < 3; ++j) {
            float o = 0.0f;
            for (int k = 0; k < M; ++k) o += facc[k] * Wm[k * 3 + j];
            for (int g = 0; g < 4; ++g)  o += go[g] * Wm[(M + g) * 3 + j];
            out[j] = o;
        }
    }
}

extern "C" void kernel_launch(void* const* d_in, const int* in_sizes, int n_in,
                              void* d_out, int out_size, void* d_ws, size_t ws_size,
                              hipStream_t stream)
{
    const float* x_member = (const float*)d_in[0];
    const float* x_group  = (const float*)d_in[1];
    const int*   edge_src = (const int*)  d_in[2];
    const int*   edge_dst = (const int*)  d_in[3];
    const float* H0       = (const float*)d_in[4];
    const float* Hs       = (const float*)d_in[5];
    const float* Wsc      = (const float*)d_in[6];
    const float* Wg       = (const float*)d_in[7];
    const float* Wm       = (const float*)d_in[8];
    float* out = (float*)d_out;

    // workspace layout — 36.1 MB (passD/off deleted; gh lives through all
    // rounds in its own region):
    //   col/ebuf : 25,600,000 B
    //   gh       :    800,768 B  (GHLEN ints)  @ 25,600,000
    //   bsum     :        784 B                @ 26,400,768
    //   xh       :  3,200,000 B  [N] fp16x8    @ 26,420,000
    //   r0b      :  3,200,000 B  [N] fp8x16    @ 29,620,000
    //   r1b      :  3,200,000 B  [N] fp8x16    @ 32,820,000
    //   facc     :         64 B                @ 36,020,000
    char* w = (char*)d_ws;
    int*    col  = (int*)w;
    int*    gh   = (int*)(w + 25600000);
    int*    bsum = gh + GHLEN;
    __half* xh   = (__half*)(w + 26420000);
    u32x4*  r0b  = (u32x4*)(w + 29620000);
    u32x4*  r1b  = (u32x4*)(w + 32820000);
    float*  facc = (float*)(w + 36020000);

    // raise dynamic-LDS cap for passC (host-side attr, graph-capture safe)
    static bool attr_done = false;
    if (!attr_done) {
        (void)hipFuncSetAttribute((const void*)passC_kernel,
                                  hipFuncAttributeMaxDynamicSharedMemorySize,
                                  PASSC_LDS_BYTES);
        attr_done = true;
    }

    (void)hipMemsetAsync(facc, 0, 64, stream);

    const int nblocks = (N_NODES + 255) / 256;    // 782

    convert_kernel<<<nblocks, 256, 0, stream>>>(x_member, xh);
    passA_kernel<<<NBLK, 1024, 0, stream>>>(edge_dst, gh);
    scan1_kernel<<<SBLOCKS, 1024, 0, stream>>>(gh, bsum);
    scan2_kernel<<<1, 256, 0, stream>>>(bsum);
    scan3_kernel<<<SBLOCKS, 1024, 0, stream>>>(gh, bsum);
    passC_kernel<<<NBLK, 1024, PASSC_LDS_BYTES, stream>>>(edge_src, edge_dst, gh, col);

    round_kernel<T, false><<<NB, 512, 0, stream>>>((const u32x4*)xh, gh, col, r0b, H0,             Wsc, 0, facc);
    round_kernel<M, true ><<<NB, 512, 0, stream>>>(r0b,              gh, col, r1b, Hs + 0 * M * M, Wsc, 1, facc);
    round_kernel<M, true ><<<NB, 512, 0, stream>>>(r1b,              gh, col, r0b, Hs + 1 * M * M, Wsc, 2, facc);
    round_kernel<M, true ><<<NB, 512, 0, stream>>>(r0b,              gh, col, r1b, Hs + 2 * M * M, Wsc, 3, facc);

    final_kernel<<<1, 64, 0, stream>>>(facc, x_group, Wg, Wm, out);
}